// Round 1
// baseline (45.637 us; speedup 1.0000x reference)
//
#include <hip/hip_runtime.h>
#include <hip/hip_bf16.h>
#include <math.h>

// ExpectSpatialSoftmax: x [32,128,128,128] f32 -> keypoints [32,128,2] f32
// softmax over H*W per (b,c), expectation against coord grid in [-1,1]^2.

#define HW 16384           // 128*128
#define ROWS 4096          // 32*128
#define THREADS 256

__global__ __launch_bounds__(THREADS)
void ess_kernel(const float* __restrict__ x, float* __restrict__ out) {
    const int row = blockIdx.x;                  // b*C + c
    const float4* p = reinterpret_cast<const float4*>(x + (size_t)row * HW);
    const int t = threadIdx.x;

    // ---- load 64 elements (16 float4) into registers, coalesced ----
    float4 v[16];
#pragma unroll
    for (int i = 0; i < 16; ++i)
        v[i] = p[i * THREADS + t];

    // ---- thread-local max ----
    float m = -INFINITY;
#pragma unroll
    for (int i = 0; i < 16; ++i)
        m = fmaxf(m, fmaxf(fmaxf(v[i].x, v[i].y), fmaxf(v[i].z, v[i].w)));

    // ---- wave (64-lane) max via butterfly ----
#pragma unroll
    for (int off = 32; off >= 1; off >>= 1)
        m = fmaxf(m, __shfl_xor(m, off));

    // ---- coordinates ----
    // element index n = i*1024 + t*4 + j  (j=0..3)
    // x-pixel = n & 127 -> constant per (t,j); y-pixel = n >> 7 = i*8 + (t*4)>>7
    const float stepc = 2.0f / 127.0f;
    const int lane4 = t * 4;
    const float xx0 = -1.0f + (float)(lane4 & 127) * stepc;   // x of .x lane
    const int y0 = lane4 >> 7;                                 // 0..7

    // ---- exp + weighted accumulation (per-wave shift m) ----
    float s = 0.f, wx = 0.f, wy = 0.f;
#pragma unroll
    for (int i = 0; i < 16; ++i) {
        float e0 = __expf(v[i].x - m);
        float e1 = __expf(v[i].y - m);
        float e2 = __expf(v[i].z - m);
        float e3 = __expf(v[i].w - m);
        float es = (e0 + e1) + (e2 + e3);
        float yy = -1.0f + (float)(i * 8 + y0) * stepc;        // same for j=0..3
        s += es;
        wy = fmaf(es, yy, wy);
        wx = fmaf(e0, xx0,             wx);
        wx = fmaf(e1, xx0 +     stepc, wx);
        wx = fmaf(e2, xx0 + 2.f*stepc, wx);
        wx = fmaf(e3, xx0 + 3.f*stepc, wx);
    }

    // ---- wave reduce s, wx, wy ----
#pragma unroll
    for (int off = 32; off >= 1; off >>= 1) {
        s  += __shfl_xor(s,  off);
        wx += __shfl_xor(wx, off);
        wy += __shfl_xor(wy, off);
    }

    // ---- combine 4 wave partials (each has its own shift m) ----
    __shared__ float red[4][4];                 // m, s, wx, wy per wave
    const int wave = t >> 6;
    if ((t & 63) == 0) {
        red[wave][0] = m;
        red[wave][1] = s;
        red[wave][2] = wx;
        red[wave][3] = wy;
    }
    __syncthreads();
    if (t == 0) {
        float M = fmaxf(fmaxf(red[0][0], red[1][0]),
                        fmaxf(red[2][0], red[3][0]));
        float S = 0.f, WX = 0.f, WY = 0.f;
#pragma unroll
        for (int w2 = 0; w2 < 4; ++w2) {
            float f = __expf(red[w2][0] - M);
            S  = fmaf(red[w2][1], f, S);
            WX = fmaf(red[w2][2], f, WX);
            WY = fmaf(red[w2][3], f, WY);
        }
        out[row * 2 + 0] = WX / S;
        out[row * 2 + 1] = WY / S;
    }
}

extern "C" void kernel_launch(void* const* d_in, const int* in_sizes, int n_in,
                              void* d_out, int out_size, void* d_ws, size_t ws_size,
                              hipStream_t stream) {
    const float* x = (const float*)d_in[0];
    float* out = (float*)d_out;
    ess_kernel<<<ROWS, THREADS, 0, stream>>>(x, out);
}

// Round 2
// 45.417 us; speedup vs baseline: 1.0048x; 1.0048x over previous
//
#include <hip/hip_runtime.h>
#include <hip/hip_bf16.h>
#include <math.h>

// ExpectSpatialSoftmax: x [32,128,128,128] f32 -> keypoints [32,128,2] f32
// softmax over H*W per (b,c), expectation against coord grid in [-1,1]^2.
// Streaming online-softmax: running max + rescale per 16-element group.
// Keeps only 2x4 float4 live -> low VGPR -> 8 waves/SIMD for max MLP.

#define HW 16384           // 128*128
#define ROWS 4096          // 32*128
#define THREADS 256

__global__ __launch_bounds__(THREADS)
void ess_kernel(const float* __restrict__ x, float* __restrict__ out) {
    const int row = blockIdx.x;                  // b*C + c
    const float4* p = reinterpret_cast<const float4*>(x + (size_t)row * HW);
    const int t = threadIdx.x;

    // coordinates: element n = i*1024 + t*4 + j  (i = float4-chunk 0..15, j=0..3)
    // x-pixel = n & 127  (constant per (t,j));  y-pixel = n>>7 = i*8 + (t*4)>>7
    const float stepc = 2.0f / 127.0f;
    const int lane4 = t * 4;
    const float xx0 = -1.0f + (float)(lane4 & 127) * stepc;
    const int y0 = lane4 >> 7;                   // 0..7

    float m = -INFINITY, s = 0.f, wx = 0.f, wy = 0.f;

    float4 cur[4], nxt[4];
#pragma unroll
    for (int k = 0; k < 4; ++k)
        cur[k] = p[k * THREADS + t];

#pragma unroll
    for (int g = 0; g < 4; ++g) {
        // prefetch next group while processing current
        if (g < 3) {
#pragma unroll
            for (int k = 0; k < 4; ++k)
                nxt[k] = p[((g + 1) * 4 + k) * THREADS + t];
        }
        // group max (16 elements)
        float gm = -INFINITY;
#pragma unroll
        for (int k = 0; k < 4; ++k)
            gm = fmaxf(gm, fmaxf(fmaxf(cur[k].x, cur[k].y),
                                 fmaxf(cur[k].z, cur[k].w)));
        // online rescale
        float mn = fmaxf(m, gm);
        float sc = __expf(m - mn);               // exp(-inf)=0 handles first group
        s *= sc; wx *= sc; wy *= sc;
        m = mn;
        // accumulate
#pragma unroll
        for (int k = 0; k < 4; ++k) {
            float e0 = __expf(cur[k].x - m);
            float e1 = __expf(cur[k].y - m);
            float e2 = __expf(cur[k].z - m);
            float e3 = __expf(cur[k].w - m);
            float es = (e0 + e1) + (e2 + e3);
            float yy = -1.0f + (float)((g * 4 + k) * 8 + y0) * stepc;
            s += es;
            wy = fmaf(es, yy, wy);
            wx = fmaf(e0, xx0,              wx);
            wx = fmaf(e1, xx0 +      stepc, wx);
            wx = fmaf(e2, xx0 + 2.f *stepc, wx);
            wx = fmaf(e3, xx0 + 3.f *stepc, wx);
        }
#pragma unroll
        for (int k = 0; k < 4; ++k) cur[k] = nxt[k];
    }

    // ---- wave (64-lane) combine: max, rescale, sum ----
    float Mw = m;
#pragma unroll
    for (int off = 32; off >= 1; off >>= 1)
        Mw = fmaxf(Mw, __shfl_xor(Mw, off));
    float c = __expf(m - Mw);
    s *= c; wx *= c; wy *= c;
#pragma unroll
    for (int off = 32; off >= 1; off >>= 1) {
        s  += __shfl_xor(s,  off);
        wx += __shfl_xor(wx, off);
        wy += __shfl_xor(wy, off);
    }

    // ---- combine 4 wave partials ----
    __shared__ float red[4][4];                  // m, s, wx, wy per wave
    const int wave = t >> 6;
    if ((t & 63) == 0) {
        red[wave][0] = Mw;
        red[wave][1] = s;
        red[wave][2] = wx;
        red[wave][3] = wy;
    }
    __syncthreads();
    if (t == 0) {
        float M = fmaxf(fmaxf(red[0][0], red[1][0]),
                        fmaxf(red[2][0], red[3][0]));
        float S = 0.f, WX = 0.f, WY = 0.f;
#pragma unroll
        for (int w2 = 0; w2 < 4; ++w2) {
            float f = __expf(red[w2][0] - M);
            S  = fmaf(red[w2][1], f, S);
            WX = fmaf(red[w2][2], f, WX);
            WY = fmaf(red[w2][3], f, WY);
        }
        out[row * 2 + 0] = WX / S;
        out[row * 2 + 1] = WY / S;
    }
}

extern "C" void kernel_launch(void* const* d_in, const int* in_sizes, int n_in,
                              void* d_out, int out_size, void* d_ws, size_t ws_size,
                              hipStream_t stream) {
    const float* x = (const float*)d_in[0];
    float* out = (float*)d_out;
    ess_kernel<<<ROWS, THREADS, 0, stream>>>(x, out);
}

// Round 4
// 43.621 us; speedup vs baseline: 1.0462x; 1.0412x over previous
//
#include <hip/hip_runtime.h>
#include <hip/hip_bf16.h>
#include <math.h>

// ExpectSpatialSoftmax: x [32,128,128,128] f32 -> keypoints [32,128,2] f32
// softmax over H*W per (b,c), expectation against coord grid in [-1,1]^2.
// Streaming online-softmax + nontemporal loads (pure stream, no cache alloc).

#define HW 16384           // 128*128
#define ROWS 4096          // 32*128
#define THREADS 256

typedef float f4 __attribute__((ext_vector_type(4)));  // native vec for nt-load

__global__ __launch_bounds__(THREADS)
void ess_kernel(const float* __restrict__ x, float* __restrict__ out) {
    const int row = blockIdx.x;                  // b*C + c
    const f4* p = reinterpret_cast<const f4*>(x + (size_t)row * HW);
    const int t = threadIdx.x;

    // coordinates: element n = i*1024 + t*4 + j  (i = float4-chunk 0..15, j=0..3)
    // x-pixel = n & 127  (constant per (t,j));  y-pixel = n>>7 = i*8 + (t*4)>>7
    const float stepc = 2.0f / 127.0f;
    const int lane4 = t * 4;
    const float xx0 = -1.0f + (float)(lane4 & 127) * stepc;
    const int y0 = lane4 >> 7;                   // 0..7

    float m = -INFINITY, s = 0.f, wx = 0.f, wy = 0.f;

    f4 cur[4], nxt[4];
#pragma unroll
    for (int k = 0; k < 4; ++k)
        cur[k] = __builtin_nontemporal_load(p + k * THREADS + t);

#pragma unroll
    for (int g = 0; g < 4; ++g) {
        // prefetch next group while processing current
        if (g < 3) {
#pragma unroll
            for (int k = 0; k < 4; ++k)
                nxt[k] = __builtin_nontemporal_load(p + ((g + 1) * 4 + k) * THREADS + t);
        }
        // group max (16 elements)
        float gm = -INFINITY;
#pragma unroll
        for (int k = 0; k < 4; ++k)
            gm = fmaxf(gm, fmaxf(fmaxf(cur[k].x, cur[k].y),
                                 fmaxf(cur[k].z, cur[k].w)));
        // online rescale
        float mn = fmaxf(m, gm);
        float sc = __expf(m - mn);               // exp(-inf)=0 handles first group
        s *= sc; wx *= sc; wy *= sc;
        m = mn;
        // accumulate
#pragma unroll
        for (int k = 0; k < 4; ++k) {
            float e0 = __expf(cur[k].x - m);
            float e1 = __expf(cur[k].y - m);
            float e2 = __expf(cur[k].z - m);
            float e3 = __expf(cur[k].w - m);
            float es = (e0 + e1) + (e2 + e3);
            float yy = -1.0f + (float)((g * 4 + k) * 8 + y0) * stepc;
            s += es;
            wy = fmaf(es, yy, wy);
            wx = fmaf(e0, xx0,              wx);
            wx = fmaf(e1, xx0 +      stepc, wx);
            wx = fmaf(e2, xx0 + 2.f *stepc, wx);
            wx = fmaf(e3, xx0 + 3.f *stepc, wx);
        }
#pragma unroll
        for (int k = 0; k < 4; ++k) cur[k] = nxt[k];
    }

    // ---- wave (64-lane) combine: max, rescale, sum ----
    float Mw = m;
#pragma unroll
    for (int off = 32; off >= 1; off >>= 1)
        Mw = fmaxf(Mw, __shfl_xor(Mw, off));
    float c = __expf(m - Mw);
    s *= c; wx *= c; wy *= c;
#pragma unroll
    for (int off = 32; off >= 1; off >>= 1) {
        s  += __shfl_xor(s,  off);
        wx += __shfl_xor(wx, off);
        wy += __shfl_xor(wy, off);
    }

    // ---- combine 4 wave partials ----
    __shared__ float red[4][4];                  // m, s, wx, wy per wave
    const int wave = t >> 6;
    if ((t & 63) == 0) {
        red[wave][0] = Mw;
        red[wave][1] = s;
        red[wave][2] = wx;
        red[wave][3] = wy;
    }
    __syncthreads();
    if (t == 0) {
        float M = fmaxf(fmaxf(red[0][0], red[1][0]),
                        fmaxf(red[2][0], red[3][0]));
        float S = 0.f, WX = 0.f, WY = 0.f;
#pragma unroll
        for (int w2 = 0; w2 < 4; ++w2) {
            float f = __expf(red[w2][0] - M);
            S  = fmaf(red[w2][1], f, S);
            WX = fmaf(red[w2][2], f, WX);
            WY = fmaf(red[w2][3], f, WY);
        }
        out[row * 2 + 0] = WX / S;
        out[row * 2 + 1] = WY / S;
    }
}

extern "C" void kernel_launch(void* const* d_in, const int* in_sizes, int n_in,
                              void* d_out, int out_size, void* d_ws, size_t ws_size,
                              hipStream_t stream) {
    const float* x = (const float*)d_in[0];
    float* out = (float*)d_out;
    ess_kernel<<<ROWS, THREADS, 0, stream>>>(x, out);
}